// Round 12
// baseline (479.065 us; speedup 1.0000x reference)
//
#include <hip/hip_runtime.h>

// Shapes (fixed by the reference)
#define BB 8
#define SS 1024
#define DD 1024
#define HH 16
#define DK 64
#define FF 4096
#define MM (BB*SS)   // 8192

typedef __attribute__((ext_vector_type(8))) short short8;
typedef __attribute__((ext_vector_type(4))) short short4v;
typedef __attribute__((ext_vector_type(4))) float floatx4;

__device__ inline short f2bf(float f) {
  union { float f; unsigned u; } v; v.f = f;
  unsigned r = (v.u + 0x7FFFu + ((v.u >> 16) & 1u)) >> 16;
  return (short)r;
}
__device__ inline float bf2f(unsigned short u) {
  union { unsigned u; float f; } v; v.u = ((unsigned)u) << 16;
  return v.f;
}

// async global->LDS, 16B per lane; lds dst = wave-uniform base + lane*16
__device__ inline void gload_lds16(const void* g, void* l) {
  __builtin_amdgcn_global_load_lds(
      (const __attribute__((address_space(1))) void*)g,
      (__attribute__((address_space(3))) void*)l, 16, 0, 0);
}

// ---------------------------------------------------------------------------
// tr64: transpose one 64x64 tile fp32 [R][C] -> bf16 [C][R]
// ---------------------------------------------------------------------------
__device__ void tr64(const float* __restrict__ s, unsigned short* __restrict__ d,
                     int R, int C, int r0, int c0, float (*ld)[68], int tid) {
  {
    int r = tid >> 2, c16 = (tid & 3) * 16;
#pragma unroll
    for (int i = 0; i < 4; ++i)
      *(float4*)(&ld[r][c16 + i * 4]) =
          *(const float4*)(s + (size_t)(r0 + r) * C + c0 + c16 + i * 4);
  }
  __syncthreads();
  int c = tid >> 2, r16 = (tid & 3) * 16;
  short8 o0, o1;
#pragma unroll
  for (int i = 0; i < 8; ++i) {
    o0[i] = f2bf(ld[r16 + i][c]);
    o1[i] = f2bf(ld[r16 + 8 + i][c]);
  }
  unsigned short* dp = d + (size_t)(c0 + c) * R + r0 + r16;
  *(short8*)(dp) = o0;
  *(short8*)(dp + 8) = o1;
}

// ---------------------------------------------------------------------------
// prep_all (R10-proven): [0,4096) src->bf16 | [4096,4864) WqkvT |
//                        [4864,4876) bqkv | [4876,5132) WoT
// ---------------------------------------------------------------------------
__global__ __launch_bounds__(256) void prep_all(
    const float* __restrict__ src,
    const float* __restrict__ Wq, const float* __restrict__ Wk,
    const float* __restrict__ Wv,
    const float* __restrict__ bq, const float* __restrict__ bk,
    const float* __restrict__ bv, const float* __restrict__ Wo,
    unsigned short* __restrict__ srcb, unsigned short* __restrict__ wqkvT,
    float* __restrict__ bqkv, unsigned short* __restrict__ woT) {
  __shared__ float ld[64][68];
  const int bid = blockIdx.x, tid = threadIdx.x;
  if (bid < 4096) {
    int i8 = (bid * 256 + tid) * 8;
    float4 a = *(const float4*)(src + i8);
    float4 b = *(const float4*)(src + i8 + 4);
    short8 o;
    o[0] = f2bf(a.x); o[1] = f2bf(a.y); o[2] = f2bf(a.z); o[3] = f2bf(a.w);
    o[4] = f2bf(b.x); o[5] = f2bf(b.y); o[6] = f2bf(b.z); o[7] = f2bf(b.w);
    *(short8*)(srcb + i8) = o;
  } else if (bid < 4864) {
    int idx = bid - 4096;
    int d0 = (idx & 15) * 64, h = (idx >> 4) & 15, z = idx >> 8;
    const float* W = (z == 0 ? Wq : z == 1 ? Wk : Wv) + (size_t)h * DD * DK;
    {
      int r = tid >> 2, c16 = (tid & 3) * 16;
#pragma unroll
      for (int i = 0; i < 4; ++i)
        *(float4*)(&ld[r][c16 + i * 4]) =
            *(const float4*)(W + (size_t)(d0 + r) * DK + c16 + i * 4);
    }
    __syncthreads();
    int dv = tid >> 2, d16 = (tid & 3) * 16;
    short8 o0, o1;
#pragma unroll
    for (int i = 0; i < 8; ++i) {
      o0[i] = f2bf(ld[d16 + i][dv]);
      o1[i] = f2bf(ld[d16 + 8 + i][dv]);
    }
    unsigned short* dst = wqkvT + (size_t)(z * 1024 + h * 64 + dv) * DD + d0 + d16;
    *(short8*)(dst) = o0;
    *(short8*)(dst + 8) = o1;
  } else if (bid < 4876) {
    int n = (bid - 4864) * 256 + tid;
    int z = n >> 10;
    const float* s = (z == 0 ? bq : z == 1 ? bk : bv);
    bqkv[n] = s[n & 1023];
  } else {
    int idx = bid - 4876;
    tr64(Wo, woT, 1024, 1024, (idx & 15) * 64, (idx >> 4) * 64, ld, tid);
  }
}

// ---------------------------------------------------------------------------
// prep2 (R10-proven): mask/w1T/w2T only (their write regions alias srcb/wqkvT,
// so this launches AFTER the QKV gemm consumes those).
//  [0,512)       maskb = bf16(mask * -1e9 * log2e)
//  [512,1536)    w1T [4096,1024]
//  [1536,2560)   w2T [1024,4096]
// ---------------------------------------------------------------------------
__global__ __launch_bounds__(256) void prep2(
    const float* __restrict__ mask,
    const float* __restrict__ W1, const float* __restrict__ W2,
    unsigned short* __restrict__ maskb, unsigned short* __restrict__ w1T,
    unsigned short* __restrict__ w2T) {
  __shared__ float ldf[64][68];
  const int bid = blockIdx.x, tid = threadIdx.x;
  if (bid < 512) {
    const float MS = -1.442695041e9f;
    int i8 = (bid * 256 + tid) * 8;
    float4 a = *(const float4*)(mask + i8);
    float4 b = *(const float4*)(mask + i8 + 4);
    short8 o;
    o[0] = f2bf(a.x * MS); o[1] = f2bf(a.y * MS);
    o[2] = f2bf(a.z * MS); o[3] = f2bf(a.w * MS);
    o[4] = f2bf(b.x * MS); o[5] = f2bf(b.y * MS);
    o[6] = f2bf(b.z * MS); o[7] = f2bf(b.w * MS);
    *(short8*)(maskb + i8) = o;
  } else if (bid < 1536) {
    int i = bid - 512;
    tr64(W1, w1T, 1024, 4096, (i & 15) * 64, (i >> 4) * 64, ldf, tid);
  } else {
    int i = bid - 1536;
    tr64(W2, w2T, 4096, 1024, (i & 63) * 64, (i >> 6) * 64, ldf, tid);
  }
}

// ---------------------------------------------------------------------------
// Shared schedule pieces (8-phase, counted vmcnt, raw s_barrier)
// ---------------------------------------------------------------------------
#define BARE __builtin_amdgcn_s_barrier()
#define VM6  asm volatile("s_waitcnt vmcnt(6)" ::: "memory")
#define VM4  asm volatile("s_waitcnt vmcnt(4)" ::: "memory")
#define VM0  asm volatile("s_waitcnt vmcnt(0)" ::: "memory")
#define PH_HINT asm volatile("s_waitcnt lgkmcnt(8)" ::: "memory")
#define PH_SYNC { \
  __builtin_amdgcn_s_barrier(); \
  asm volatile("s_waitcnt lgkmcnt(0)" ::: "memory"); \
  __builtin_amdgcn_sched_barrier(0); }

// ---------------------------------------------------------------------------
// gemm256: 256x256x(BK=64), 8 waves (2M x 4N), 512 threads, 128 KiB LDS.
// ---------------------------------------------------------------------------
#define LOAD_A(lA_, mh_) { \
  _Pragma("unroll") for (int m_ = 0; m_ < 4; ++m_) { \
    const int row_ = wr * 128 + (mh_) * 64 + m_ * 16 + lm; \
    _Pragma("unroll") for (int ks_ = 0; ks_ < 2; ++ks_) \
      a[m_][ks_] = *(const short8*)((lA_) + (size_t)row_ * 64 + \
                     (size_t)(((ks_ * 4 + quad) ^ (lm & 7)) * 8)); \
  } }

#define LOAD_B(lB_, nh_) { \
  _Pragma("unroll") for (int n_ = 0; n_ < 2; ++n_) { \
    const int row_ = wc * 64 + (nh_) * 32 + n_ * 16 + lm; \
    _Pragma("unroll") for (int ks_ = 0; ks_ < 2; ++ks_) \
      bfr[nh_][n_][ks_] = *(const short8*)((lB_) + 16384 + (size_t)row_ * 64 + \
                     (size_t)(((ks_ * 4 + quad) ^ (lm & 7)) * 8)); \
  } }

#define STAGE_A(kt_, mh_, lb_) { \
  _Pragma("unroll") for (int c_ = 0; c_ < 2; ++c_) { \
    const int row_ = c_ * 128 + (mh_) * 64; \
    gload_lds16(gA + (size_t)(kt_) * 64 + (size_t)row_ * K, \
                (lb_) + (size_t)(row_ + wave * 8) * 64); \
  } }

#define STAGE_B(kt_, nh_, lb_) { \
  _Pragma("unroll") for (int c_ = 0; c_ < 2; ++c_) { \
    const int row_ = c_ * 128 + hi128 + (nh_) * 32; \
    gload_lds16(gB + (size_t)(kt_) * 64 + (size_t)row_ * K, \
                (lb_) + 16384 + (size_t)(row_ + (wave & 3) * 8) * 64); \
  } }

#define MFMA_PH(mh_, nh_) { \
  __builtin_amdgcn_s_setprio(1); \
  _Pragma("unroll") for (int m_ = 0; m_ < 4; ++m_) \
    _Pragma("unroll") for (int n_ = 0; n_ < 2; ++n_) { \
      acc[(mh_) * 4 + m_][(nh_) * 2 + n_] = __builtin_amdgcn_mfma_f32_16x16x32_bf16( \
          bfr[nh_][n_][0], a[m_][0], acc[(mh_) * 4 + m_][(nh_) * 2 + n_], 0, 0, 0); \
      acc[(mh_) * 4 + m_][(nh_) * 2 + n_] = __builtin_amdgcn_mfma_f32_16x16x32_bf16( \
          bfr[nh_][n_][1], a[m_][1], acc[(mh_) * 4 + m_][(nh_) * 2 + n_], 0, 0, 0); \
    } \
  __builtin_amdgcn_s_setprio(0); }

// ST_ = 1: steady iteration (stages tiles e+2, e+3); ST_ = 0: peeled tail.
#define KITER(e_, ST_) { \
  LOAD_A(buf0, 0); LOAD_B(buf0, 0); \
  STAGE_B((e_) + 1, 1, buf1); \
  PH_HINT; PH_SYNC; MFMA_PH(0, 0); BARE; \
  LOAD_B(buf0, 1); \
  if (ST_) STAGE_A((e_) + 2, 0, buf0); \
  PH_SYNC; MFMA_PH(0, 1); BARE; \
  LOAD_A(buf0, 1); \
  if (ST_) STAGE_B((e_) + 2, 0, buf0); \
  PH_SYNC; MFMA_PH(1, 0); BARE; \
  if (ST_) STAGE_A((e_) + 2, 1, buf0); \
  PH_SYNC; MFMA_PH(1, 1); \
  if (ST_) { VM6; } else { VM0; } \
  BARE; \
  LOAD_A(buf1, 0); LOAD_B(buf1, 0); \
  if (ST_) STAGE_B((e_) + 2, 1, buf0); \
  PH_HINT; PH_SYNC; MFMA_PH(0, 0); BARE; \
  LOAD_B(buf1, 1); \
  if (ST_) STAGE_A((e_) + 3, 0, buf1); \
  PH_SYNC; MFMA_PH(0, 1); BARE; \
  LOAD_A(buf1, 1); \
  if (ST_) STAGE_B((e_) + 3, 0, buf1); \
  PH_SYNC; MFMA_PH(1, 0); BARE; \
  if (ST_) { \
    STAGE_A((e_) + 3, 1, buf1); \
    PH_SYNC; MFMA_PH(1, 1); VM6; BARE; \
  } else { \
    PH_SYNC; MFMA_PH(1, 1); \
  } }

template <int RELU>
__global__ __launch_bounds__(512, 2) void gemm256(
    const unsigned short* __restrict__ A, const unsigned short* __restrict__ Bt,
    const float* __restrict__ bias, unsigned short* __restrict__ C,
    int M, int N, int K) {
  extern __shared__ unsigned short lds[];  // [buf0 | buf1], each A16384|B16384
  unsigned short* buf0 = lds;
  unsigned short* buf1 = lds + 32768;
  const int tid = threadIdx.x;
  const int wave = tid >> 6, lane = tid & 63;
  const int lm = lane & 15, quad = lane >> 4;
  const int wr = wave >> 2, wc = wave & 3;

  // XCD-aware bijective swizzle (all grids here are multiples of 8)
  const int nwg = gridDim.x;
  const int cpx = nwg >> 3;
  const int id = (blockIdx.x & 7) * cpx + (blockIdx.x >> 3);
  const int nbx = N >> 8;
  const int bx = id % nbx, by = id / nbx;
  const int n0 = bx << 8, m0 = by << 8;

  const int NT = K >> 6;   // 64-wide K-tiles

  const int srow = tid >> 3;                    // 0..63
  const int chs = (tid & 7) ^ (srow & 7);
  const int hi128 = (tid >= 256) ? 64 : 0;
  const int r32 = (tid >> 3) & 31;
  const unsigned short* gA = A + (size_t)(m0 + srow) * K + chs * 8;
  const unsigned short* gB = Bt + (size_t)(n0 + r32) * K + chs * 8;

  floatx4 acc[8][4] = {};
  short8 a[4][2], bfr[2][2][2];

  // prologue: tile0 full (8 loads) + tile1 {A.h0, B.h0, A.h1} (6 loads)
  STAGE_A(0, 0, buf0); STAGE_B(0, 0, buf0);
  STAGE_A(0, 1, buf0); STAGE_B(0, 1, buf0);
  STAGE_A(1, 0, buf1); STAGE_B(1, 0, buf1);
  STAGE_A(1, 1, buf1);
  VM6;   // retire tile0's 8, leave tile1's 6 in flight
  BARE;

  const int TT = NT >> 1;
  for (int i = 0; i < TT - 1; ++i) {
    KITER(2 * i, 1);
  }
  KITER(NT - 2, 0);

  // epilogue: bias (+ReLU) + bf16 store, per-lane 8B stores
#pragma unroll
  for (int mi = 0; mi < 8; ++mi) {
    const int row = m0 + wr * 128 + mi * 16 + lm;
#pragma unroll
    for (int nj = 0; nj < 4; ++nj) {
      const int col = n0 + wc * 64 + nj * 16 + (quad << 2);
      const float4 bv = *(const float4*)(bias + col);
      float vv[4] = {acc[mi][nj][0] + bv.x, acc[mi][nj][1] + bv.y,
                     acc[mi][nj][2] + bv.z, acc[mi][nj][3] + bv.w};
      short4v o;
#pragma unroll
      for (int r = 0; r < 4; ++r) {
        float v = vv[r];
        if (RELU) v = fmaxf(v, 0.f);
        o[r] = f2bf(v);
      }
      *(short4v*)(C + (size_t)row * N + col) = o;
    }
  }
}

// ---------------------------------------------------------------------------
// gemm128: 128x256x(BK=64) variant of the SAME 8-phase schedule.
// kdst/vdst (optional): blocks whose n0 lies in [1024,2048) / [2048,3072)
// write output directly in kbb [bh][t][dk] / vtb [bh][dv][t] layouts.
// ---------------------------------------------------------------------------
#define LOAD_A1(lb_, mh_) { \
  _Pragma("unroll") for (int m_ = 0; m_ < 2; ++m_) { \
    const int row_ = wr * 64 + (mh_) * 32 + m_ * 16 + lm; \
    _Pragma("unroll") for (int ks_ = 0; ks_ < 2; ++ks_) \
      a[m_][ks_] = *(const short8*)((lb_) + (size_t)row_ * 64 + \
                     (size_t)(((ks_ * 4 + quad) ^ (lm & 7)) * 8)); \
  } }

#define LOAD_B1(lb_, nh_) { \
  _Pragma("unroll") for (int n_ = 0; n_ < 2; ++n_) { \
    const int row_ = wc * 64 + (nh_) * 32 + n_ * 16 + lm; \
    _Pragma("unroll") for (int ks_ = 0; ks_ < 2; ++ks_) \
      bfr[nh_][n_][ks_] = *(const short8*)((lb_) + 8192 + (size_t)row_ * 64 + \
                     (size_t)(((ks_ * 4 + quad) ^ (lm & 7)) * 8)); \
  } }

#define STAGE_A1(kt_, mh_, lb_) { \
  gload_lds16(gA + (size_t)(kt_) * 64 + (size_t)((mh_) * 32) * K, \
              (lb_) + (size_t)((mh_) * 32 + hi128 + (wave & 3) * 8) * 64); }

#define STAGE_B1(kt_, nh_, lb_) { \
  _Pragma("unroll") for (int c_ = 0; c_ < 2; ++c_) { \
    const int row_ = c_ * 128 + hi128 + (nh_) * 32; \
    gload_lds16(gB + (size_t)(kt_) * 64 + (size_t)row_ * K, \
                (lb_) + 8192 + (size_t)(row_ + (wave & 3) * 8) * 64); \
  } }

#define MFMA_PH1(mh_, nh_) { \
  __builtin_amdgcn_s_setprio(1); \
  _Pragma("unroll") for (int m_ = 0; m_ < 2; ++m_) \
    _Pragma("unroll") for (int n_ = 0; n_ < 2; ++n_) { \
      acc[(mh_) * 2 + m_][(nh_) * 2 + n_] = __builtin_amdgcn_mfma_f32_16x16x32_bf16( \
          bfr[nh_][n_][0], a[m_][0], acc[(mh_) * 2 + m_][(nh_) * 2 + n_], 0, 0, 0); \
      acc[(mh_) * 2 + m_][(nh_) * 2 + n_] = __builtin_amdgcn_mfma_f32_16x16x32_bf16( \
          bfr[nh_][n_][1], a[m_][1], acc[(mh_) * 2 + m_][(nh_) * 2 + n_], 0, 0, 0); \
    } \
  __builtin_amdgcn_s_setprio(0); }

#define KITER1(e_, ST_) { \
  LOAD_A1(buf0, 0); LOAD_B1(buf0, 0); \
  STAGE_B1((e_) + 1, 1, buf1); \
  PH_SYNC; MFMA_PH1(0, 0); BARE; \
  LOAD_B1(buf0, 1); \
  if (ST_) STAGE_A1((e_) + 2, 0, buf0); \
  PH_SYNC; MFMA_PH1(0, 1); BARE; \
  LOAD_A1(buf0, 1); \
  if (ST_) STAGE_B1((e_) + 2, 0, buf0); \
  PH_SYNC; MFMA_PH1(1, 0); BARE; \
  if (ST_) STAGE_A1((e_) + 2, 1, buf0); \
  PH_SYNC; MFMA_PH1(1, 1); \
  if (ST_) { VM4; } else { VM0; } \
  BARE; \
  LOAD_A1(buf1, 0); LOAD_B1(buf1, 0); \
  if (ST_) STAGE_B1((e_) + 2, 1, buf0); \
  PH_SYNC; MFMA_PH1(0, 0); BARE; \
  LOAD_B1(buf1, 1); \
  if (ST_) STAGE_A1((e_) + 3, 0, buf1); \
  PH_SYNC; MFMA_PH1(0, 1); BARE; \
  LOAD_A1(buf1, 1); \
  if (ST_) STAGE_B1((e_) + 3, 0, buf1); \
  PH_SYNC; MFMA_PH1(1, 0); BARE; \
  if (ST_) { \
    STAGE_A1((e_) + 3, 1, buf1); \
    PH_SYNC; MFMA_PH1(1, 1); VM4; BARE; \
  } else { \
    PH_SYNC; MFMA_PH1(1, 1); \
  } }

__global__ __launch_bounds__(512, 2) void gemm128(
    const unsigned short* __restrict__ A, const unsigned short* __restrict__ Bt,
    const float* __restrict__ bias, unsigned short* __restrict__ C,
    unsigned short* __restrict__ kdst, unsigned short* __restrict__ vdst,
    int M, int N, int K) {
  extern __shared__ unsigned short lds[];  // 2 bufs x (A 8192 | B 16384) elems
  unsigned short* buf0 = lds;
  unsigned short* buf1 = lds + 24576;
  const int tid = threadIdx.x;
  const int wave = tid >> 6, lane = tid & 63;
  const int lm = lane & 15, quad = lane >> 4;
  const int wr = wave >> 2, wc = wave & 3;

  const int nwg = gridDim.x;
  const int cpx = nwg >> 3;
  const int id = (blockIdx.x & 7) * cpx + (blockIdx.x >> 3);
  const int nbx = N >> 8;
  const int bx = id % nbx, by = id / nbx;
  const int n0 = bx << 8, m0 = by << 7;   // BM = 128

  const int NT = K >> 6;

  const int srow = tid >> 3;
  const int chs = (tid & 7) ^ (srow & 7);
  const int hi128 = (tid >= 256) ? 64 : 0;
  const int r32 = (tid >> 3) & 31;
  // A global row = m0 + hi128 + mh*32 + r32  (matches LDS row mh*32+hi128+r32)
  const unsigned short* gA = A + (size_t)(m0 + hi128 + r32) * K + chs * 8;
  const unsigned short* gB = Bt + (size_t)(n0 + r32) * K + chs * 8;

  floatx4 acc[4][4] = {};
  short8 a[2][2], bfr[2][2][2];

  // prologue: tile0 full (6 loads) + tile1 {A.H0, B.h0, A.H1} (4 loads)
  STAGE_A1(0, 0, buf0); STAGE_B1(0, 0, buf0);
  STAGE_A1(0, 1, buf0); STAGE_B1(0, 1, buf0);
  STAGE_A1(1, 0, buf1); STAGE_B1(1, 0, buf1);
  STAGE_A1(1, 1, buf1);
  VM4;   // retire tile0's 6, leave tile1's 4 in flight
  BARE;

  const int TT = NT >> 1;
  for (int i = 0; i < TT - 1; ++i) {
    KITER1(2 * i, 1);
  }
  KITER1(NT - 2, 0);

  const bool kdirect = (kdst != nullptr) && (n0 >= 1024) && (n0 < 2048);
  const bool vdirect = (vdst != nullptr) && (n0 >= 2048) && (n0 < 3072);
#pragma unroll
  for (int mi = 0; mi < 4; ++mi) {
    const int row = m0 + wr * 64 + mi * 16 + lm;
#pragma unroll
    for (int nj = 0; nj < 4; ++nj) {
      const int col = n0 + wc * 64 + nj * 16 + (quad << 2);
      const float4 bv = *(const float4*)(bias + col);
      short4v o;
      o[0] = f2bf(acc[mi][nj][0] + bv.x);
      o[1] = f2bf(acc[mi][nj][1] + bv.y);
      o[2] = f2bf(acc[mi][nj][2] + bv.z);
      o[3] = f2bf(acc[mi][nj][3] + bv.w);
      if (kdirect) {
        // kbb[(b*16+h)][t][dk]: b=row>>10, t=row&1023, h=(col-1024)>>6, dk=col&63
        const int b_ = row >> 10, t_ = row & 1023;
        const int rel = col - 1024;
        const int h_ = rel >> 6, dk = rel & 63;
        *(short4v*)(kdst + ((size_t)(b_ * 16 + h_) * 1024 + t_) * 64 + dk) = o;
      } else if (vdirect) {
        // vtb[(b*16+h)][dv][t]: dv = col&63 (4 consecutive dv per lane)
        const int b_ = row >> 10, t_ = row & 1023;
        const int rel = col - 2048;
        const int h_ = rel >> 6, dv = rel & 63;
        unsigned short* vp = vdst + ((size_t)(b_ * 16 + h_) * 64 + dv) * 1024 + t_;
        vp[0]    = (unsigned short)o[0];
        vp[1024] = (unsigned short)o[1];
        vp[2048] = (unsigned short)o[2];
        vp[3072] = (unsigned short)o[3];
      } else {
        *(short4v*)(C + (size_t)row * N + col) = o;
      }
    }
  }
}

// ---------------------------------------------------------------------------
// Flash attention. LDS cut 50KB -> 32KB (4 blocks/CU = 32 waves -> the full
// 1024-block grid resident in ONE round; was 3/CU + straggler round).
// Ps buffer eliminated: P is wave-private and each wave reads ONLY its own
// 16 Ms rows (mask consumed into registers, data-dep, before P-stores), so
// P aliases the wave's own Ms rows [wave*16,+16). Per-row 8B-granule XOR
// (g ^ lm) on store AND read (bijective; t-contiguous un-swizzled layout
// identical to the proven Ps layout). PV completes before the top-of-loop
// __syncthreads that guards next-tile Ms restaging.
// ---------------------------------------------------------------------------
__global__ __launch_bounds__(512) void attention_flash(
    const unsigned short* __restrict__ qkv, const unsigned short* __restrict__ kb,
    const unsigned short* __restrict__ vt, const unsigned short* __restrict__ maskb,
    unsigned short* __restrict__ ctx) {
  const int flat = blockIdx.x;
  const int bh = (flat & 7) + 8 * (flat >> 6);       // all q-tiles of a bh on one XCD
  const int qt = (flat >> 3) & 7;
  const int b = bh >> 4, h = bh & 15;
  const int s0 = qt * 128;
  const int tid = threadIdx.x;
  const int wave = tid >> 6, lane = tid & 63;
  const int lm = lane & 15, quad = lane >> 4;

  __shared__ __align__(16) unsigned short Ks[64 * 64];     //  8 KB swizzled [t][dk]
  __shared__ __align__(16) unsigned short Vs[64 * 64];     //  8 KB swizzled [dv][t]
  __shared__ __align__(16) unsigned short Ms[128 * 64];    // 16 KB swizzled [q][t]; P aliases per-wave rows

  // Q fragments (once): q-row = s0 + wave*16 + lm
  const unsigned short* qp = qkv + (size_t)(b * SS + s0 + wave * 16 + lm) * 3072 + h * 64;
  const short8 qa0 = *(const short8*)(qp + quad * 8);
  const short8 qa1 = *(const short8*)(qp + quad * 8 + 32);

  const unsigned short* kbase = kb + (size_t)bh * SS * DK;   // [t][dk]
  const unsigned short* vbase = vt + (size_t)bh * DK * SS;   // [dv][t]
  const unsigned short* mbase = maskb + (size_t)s0 * SS;     // [q][t]

  const int sr = lane >> 3, sj = lane & 7;   // staging row-in-8 / chunk
  const int srr = wave * 8 + sr;
  const unsigned short* ksrc = kbase + (size_t)srr * 64 + (size_t)(sj ^ (srr & 7)) * 8;
  const int qr = wave * 16 + lm;
  unsigned short* pr = &Ms[(unsigned)qr * 64];   // wave-private P rows (alias)
  float m_run = -3e38f, l_run = 0.f;
  floatx4 O[4] = {};

  for (int it = 0; it < 16; ++it) {
    const int t0 = it * 64;
    __syncthreads();   // previous compute done before tiles overwritten
    {
      // K: slots [wave*64, +64): r = srr, chunk = sj^(r&7)
      gload_lds16(ksrc + (size_t)t0 * 64, (char*)Ks + wave * 1024);
      // V^T: r = dv
      gload_lds16(vbase + (size_t)srr * SS + t0 + (size_t)(sj ^ (srr & 7)) * 8,
                  (char*)Vs + wave * 1024);
      // mask: 2 slots per thread
      int q1 = wave * 8 + sr;
      gload_lds16(mbase + (size_t)q1 * SS + t0 + (size_t)(sj ^ (q1 & 7)) * 8,
                  (char*)Ms + wave * 1024);
      int q2 = 64 + wave * 8 + sr;
      gload_lds16(mbase + (size_t)q2 * SS + t0 + (size_t)(sj ^ (q2 & 7)) * 8,
                  (char*)Ms + 8192 + wave * 1024);
    }
    __syncthreads();

    // ---- S = K-tile x Q (D[t][q]); lane collects 16 t-values for q=lm ----
    float p[16];
#pragma unroll
    for (int ts = 0; ts < 4; ++ts) {
      int r = ts * 16 + lm;
      short8 kf0 = *(const short8*)&Ks[(r * 8 + (quad ^ (r & 7))) * 8];
      short8 kf1 = *(const short8*)&Ks[(r * 8 + ((quad + 4) ^ (r & 7))) * 8];
      floatx4 c = {0.f, 0.f, 0.f, 0.f};
      c = __builtin_amdgcn_mfma_f32_16x16x32_bf16(kf0, qa0, c, 0, 0, 0);
      c = __builtin_amdgcn_mfma_f32_16x16x32_bf16(kf1, qa1, c, 0, 0, 0);
      int mj = (ts * 2 + (quad >> 1)) ^ (qr & 7);
      short4v mv = *(const short4v*)&Ms[(qr * 8 + mj) * 8 + (quad & 1) * 4];
#pragma unroll
      for (int r2 = 0; r2 < 4; ++r2) {
        // exp2-domain score: qk * 0.125 * log2e + (mask * -1e9 * log2e)
        p[ts * 4 + r2] = c[r2] * 0.18033688011112042f + bf2f((unsigned short)mv[r2]);
      }
    }
    // max tree (clang fuses to v_max3_f32)
    float m0a = fmaxf(fmaxf(p[0], p[1]), p[2]);
    float m0b = fmaxf(fmaxf(p[3], p[4]), p[5]);
    float m0c = fmaxf(fmaxf(p[6], p[7]), p[8]);
    float m0d = fmaxf(fmaxf(p[9], p[10]), p[11]);
    float m0e = fmaxf(fmaxf(p[12], p[13]), p[14]);
    float mt = fmaxf(fmaxf(fmaxf(m0a, m0b), m0c), fmaxf(fmaxf(m0d, m0e), p[15]));
    mt = fmaxf(mt, __shfl_xor(mt, 16));
    mt = fmaxf(mt, __shfl_xor(mt, 32));
    // T13 defer-max (log2 domain): THR = 8*log2e -> P bounded by e^8.
    if (!__all(mt - m_run <= 11.541560327f)) {
      float mnew = fmaxf(m_run, mt);
      float alpha = __builtin_amdgcn_exp2f(m_run - mnew);
#pragma unroll
      for (int d = 0; d < 4; ++d)
#pragma unroll
        for (int r2 = 0; r2 < 4; ++r2) O[d][r2] *= alpha;
      l_run *= alpha;
      m_run = mnew;
    }
    float psum = 0.f;
#pragma unroll
    for (int i = 0; i < 16; ++i) {
      p[i] = __builtin_amdgcn_exp2f(p[i] - m_run);
      psum += p[i];
    }
    psum += __shfl_xor(psum, 16);
    psum += __shfl_xor(psum, 32);
    l_run += psum;

    // ---- P -> wave's own Ms rows (alias; mask already consumed above).
    // Granule g = (ts*4+quad)^lm holds t-values [ts*16+quad*4,+4) (bijective,
    // t-contiguous un-swizzled — same logical layout as the proven Ps). ----
#pragma unroll
    for (int ts = 0; ts < 4; ++ts) {
      unsigned plo, phi;
      asm("v_cvt_pk_bf16_f32 %0, %1, %2" : "=v"(plo) : "v"(p[ts * 4 + 0]), "v"(p[ts * 4 + 1]));
      asm("v_cvt_pk_bf16_f32 %0, %1, %2" : "=v"(phi) : "v"(p[ts * 4 + 2]), "v"(p[ts * 4 + 3]));
      uint2 pu; pu.x = plo; pu.y = phi;
      *(uint2*)(pr + (((ts * 4 + quad) ^ lm) << 2)) = pu;
    }

    // ---- PV: O^T[dv][q] += V^T-tile x P^T ----
#pragma unroll
    for (int ks = 0; ks < 2; ++ks) {
      union { unsigned u[4]; short8 s; } pf;
      {
        const int gb = ks * 8 + quad * 2;
        uint2 lo = *(const uint2*)(pr + (((gb) ^ lm) << 2));
        uint2 hi = *(const uint2*)(pr + (((gb + 1) ^ lm) << 2));
        pf.u[0] = lo.x; pf.u[1] = lo.y; pf.u[2] = hi.x; pf.u[3] = hi.y;
      }
#pragma unroll
      for (int d = 0; d < 4; ++d) {
        int dv = d * 16 + lm;
        short8 vf = *(const short8*)&Vs[(dv * 8 + ((ks * 4 + quad) ^ (dv & 7))) * 8];
        O[d] = __builtin_amdgcn_mfma_f32_16x16x32_bf16(vf, pf.s, O[d], 0, 0, 0);
      }
    }
  }

  // ---- epilogue: normalize, store ctx[b, s0+qr, h*64+dv] ----
  const float inv = 1.f / l_run;
  unsigned short* cp = ctx + (size_t)(b * SS + s0 + wave * 16 + lm) * DD + h * 64;
#pragma unroll
  for (int d = 0; d < 4; ++d) {
    short4v o;
#pragma unroll
    for (int r2 = 0; r2 < 4; ++r2) o[r2] = f2bf(O[d][r2] * inv);
    *(short4v*)(cp + d * 16 + quad * 4) = o;
  }
}

// ---------------------------------------------------------------------------
// Residual + LayerNorm: out = LN(a + r) * w + b. One block per row (D=1024).
// ---------------------------------------------------------------------------
template <int A_BF16, int OUT_BF16>
__global__ __launch_bounds__(256) void residual_ln(
    const void* __restrict__ a_, const unsigned short* __restrict__ rr,
    const float* __restrict__ w, const float* __restrict__ bias,
    void* __restrict__ out_) {
  const int row = blockIdx.x;
  const int t = threadIdx.x;
  float x[4];
  if (A_BF16) {
    short4v va = *(const short4v*)((const unsigned short*)a_ + (size_t)row * DD + t * 4);
#pragma unroll
    for (int i = 0; i < 4; ++i) x[i] = bf2f((unsigned short)va[i]);
  } else {
    float4 va = *(const float4*)((const float*)a_ + (size_t)row * DD + t * 4);
    x[0] = va.x; x[1] = va.y; x[2] = va.z; x[3] = va.w;
  }
  {
    short4v vr = *(const short4v*)(rr + (size_t)row * DD + t * 4);
#pragma unroll
    for (int i = 0; i < 4; ++i) x[i] += bf2f((unsigned short)vr[i]);
  }
  float s = 0.f, ss = 0.f;
#pragma unroll
  for (int i = 0; i < 4; ++i) { s += x[i]; ss += x[i] * x[i]; }
#pragma unroll
  for (int o = 32; o > 0; o >>= 1) {
    s  += __shfl_down(s, o);
    ss += __shfl_down(ss, o);
  }
  __shared__ float2 sred[4];
  int wid = t >> 6;
  if ((t & 63) == 0) sred[wid] = make_float2(s, ss);
  __syncthreads();
  float st = 0.f, sst = 0.f;
#pragma unroll
  for (int i = 0; i < 4; ++i) { st += sred[i].x; sst += sred[i].y; }
  float mu  = st * (1.f / 1024.f);
  float var = sst * (1.f / 1024.f) - mu * mu;
  float rsq = rsqrtf(var + 1e-5f);
  float4 vw = *(const float4*)(w + t * 4);
  float4 vb = *(const float4*)(bias + t * 4);
  float o[4];
  o[0] = (x[0] - mu) * rsq * vw.x + vb.x;
  o[1] = (x[1] - mu) * rsq * vw.y + vb.y;
  o[2] = (x[2] - mu) * rsq * vw.z + vb.z;
  o[3] = (x[3] - mu) * rsq * vw.w + vb.w;
  if (OUT_BF16) {
    short4v ov;
#pragma unroll
    for (int i = 0; i < 4; ++i) ov[i] = f2bf(o[i]);
    *(short4v*)((unsigned short*)out_ + (size_t)row * DD + t * 4) = ov;
  } else {
    float4 ov = {o[0], o[1], o[2], o[3]};
    *(float4*)((float*)out_ + (size_t)row * DD + t * 4) = ov;
  }
}

// ---------------------------------------------------------------------------
extern "C" void kernel_launch(void* const* d_in, const int* in_sizes, int n_in,
                              void* d_out, int out_size, void* d_ws, size_t ws_size,
                              hipStream_t stream) {
  const float* src  = (const float*)d_in[0];
  const float* mask = (const float*)d_in[1];
  const float* Wq = (const float*)d_in[2];  const float* bq = (const float*)d_in[3];
  const float* Wk = (const float*)d_in[4];  const float* bk = (const float*)d_in[5];
  const float* Wv = (const float*)d_in[6];  const float* bv = (const float*)d_in[7];
  const float* Wo = (const float*)d_in[8];  const float* bo = (const float*)d_in[9];
  const float* ln1w = (const float*)d_in[10]; const float* ln1b = (const float*)d_in[11];
  const float* W1 = (const float*)d_in[12]; const float* b1 = (const float*)d_in[13];
  const float* W2 = (const float*)d_in[14]; const float* b2 = (const float*)d_in[15];
  const float* ln2w = (const float*)d_in[16]; const float* ln2b = (const float*)d_in[17];
  float* out = (float*)d_out;

  // Workspace (total 125,841,408 B, same as proven):
  const size_t NEED = 125841408;
  if (ws_size < NEED) return;

  char* ws = (char*)d_ws;
  unsigned short* qkv   = (unsigned short*)(ws);
  unsigned short* vtb   = (unsigned short*)(ws + 50331648);
  unsigned short* kbb   = (unsigned short*)(ws + 67108864);
  unsigned short* ctxb  = (unsigned short*)(ws + 83886080);
  unsigned short* srcb  = (unsigned short*)(ws + 100663296);
  unsigned short* w1T   = (unsigned short*)(ws + 100663296);  // [4096,1024] (after QKV)
  unsigned short* w2T   = (unsigned short*)(ws + 109051904);  // [1024,4096]
  unsigned short* wqkvT = (unsigned short*)(ws + 117440512);  // [3072,1024]
  unsigned short* maskb = (unsigned short*)(ws + 117440512);  // [S,S] bf16 (after QKV)
  unsigned short* woT   = (unsigned short*)(ws + 123731968);  // [1024,1024]
  float*          bqkv  = (float*)(ws + 125829120);           // [3072]
  unsigned short* h1       = qkv;                             // [M,4096] = [0,64M)
  unsigned short* attn_out = kbb;
  unsigned short* xb       = ctxb;
  unsigned short* ffn      = kbb;

  static bool lds_init = false;
  if (!lds_init) {
    auto* k1 = gemm256<1>;
    hipFuncSetAttribute((const void*)k1, hipFuncAttributeMaxDynamicSharedMemorySize, 131072);
    hipFuncSetAttribute((const void*)gemm128, hipFuncAttributeMaxDynamicSharedMemorySize, 98304);
    lds_init = true;
  }

  prep_all<<<5132, 256, 0, stream>>>(src, Wq, Wk, Wv, bq, bk, bv, Wo,
                                     srcb, wqkvT, bqkv, woT);
  // QKV: [8192,3072]; K-slice -> kbb layout, V-slice -> vtb layout (direct)
  gemm128<<<(3072 / 256) * (MM / 128), 512, 98304, stream>>>(srcb, wqkvT, bqkv, qkv, kbb, vtb, MM, 3072, DD);
  // mask/w1T/w2T (write regions alias srcb/wqkvT -> must follow QKV gemm)
  prep2<<<2560, 256, 0, stream>>>(mask, W1, W2, maskb, w1T, w2T);
  attention_flash<<<1024, 512, 0, stream>>>(qkv, kbb, vtb, maskb, ctxb);
  // Wo: [8192,1024] (BM=128 -> 256 blocks, full machine)
  gemm128<<<(DD / 256) * (MM / 128), 512, 98304, stream>>>(ctxb, woT, bo, attn_out, nullptr, nullptr, MM, DD, DD);
  residual_ln<0, 1><<<MM, 256, 0, stream>>>(src, attn_out, ln1w, ln1b, xb);
  // FFN1: [8192,4096] (256^2 -> 512 blocks)
  gemm256<1><<<(FF / 256) * (MM / 256), 512, 131072, stream>>>(xb, w1T, b1, h1, MM, FF, DD);
  // FFN2: [8192,1024], K=4096 (BM=128 -> 256 blocks, full machine)
  gemm128<<<(DD / 256) * (MM / 128), 512, 98304, stream>>>(h1, w2T, b2, ffn, nullptr, nullptr, MM, DD, FF);
  residual_ln<1, 0><<<MM, 256, 0, stream>>>(xb, ffn, ln2w, ln2b, out);
}

// Round 13
// 461.774 us; speedup vs baseline: 1.0374x; 1.0374x over previous
//
#include <hip/hip_runtime.h>

// Shapes (fixed by the reference)
#define BB 8
#define SS 1024
#define DD 1024
#define HH 16
#define DK 64
#define FF 4096
#define MM (BB*SS)   // 8192

typedef __attribute__((ext_vector_type(8))) short short8;
typedef __attribute__((ext_vector_type(4))) short short4v;
typedef __attribute__((ext_vector_type(4))) float floatx4;

__device__ inline short f2bf(float f) {
  union { float f; unsigned u; } v; v.f = f;
  unsigned r = (v.u + 0x7FFFu + ((v.u >> 16) & 1u)) >> 16;
  return (short)r;
}
__device__ inline float bf2f(unsigned short u) {
  union { unsigned u; float f; } v; v.u = ((unsigned)u) << 16;
  return v.f;
}

// async global->LDS, 16B per lane; lds dst = wave-uniform base + lane*16
__device__ inline void gload_lds16(const void* g, void* l) {
  __builtin_amdgcn_global_load_lds(
      (const __attribute__((address_space(1))) void*)g,
      (__attribute__((address_space(3))) void*)l, 16, 0, 0);
}

// ---------------------------------------------------------------------------
// tr64: transpose one 64x64 tile fp32 [R][C] -> bf16 [C][R]
// ---------------------------------------------------------------------------
__device__ void tr64(const float* __restrict__ s, unsigned short* __restrict__ d,
                     int R, int C, int r0, int c0, float (*ld)[68], int tid) {
  {
    int r = tid >> 2, c16 = (tid & 3) * 16;
#pragma unroll
    for (int i = 0; i < 4; ++i)
      *(float4*)(&ld[r][c16 + i * 4]) =
          *(const float4*)(s + (size_t)(r0 + r) * C + c0 + c16 + i * 4);
  }
  __syncthreads();
  int c = tid >> 2, r16 = (tid & 3) * 16;
  short8 o0, o1;
#pragma unroll
  for (int i = 0; i < 8; ++i) {
    o0[i] = f2bf(ld[r16 + i][c]);
    o1[i] = f2bf(ld[r16 + 8 + i][c]);
  }
  unsigned short* dp = d + (size_t)(c0 + c) * R + r0 + r16;
  *(short8*)(dp) = o0;
  *(short8*)(dp + 8) = o1;
}

// ---------------------------------------------------------------------------
// prep_all (R10-proven): [0,4096) src->bf16 | [4096,4864) WqkvT |
//                        [4864,4876) bqkv | [4876,5132) WoT
// ---------------------------------------------------------------------------
__global__ __launch_bounds__(256) void prep_all(
    const float* __restrict__ src,
    const float* __restrict__ Wq, const float* __restrict__ Wk,
    const float* __restrict__ Wv,
    const float* __restrict__ bq, const float* __restrict__ bk,
    const float* __restrict__ bv, const float* __restrict__ Wo,
    unsigned short* __restrict__ srcb, unsigned short* __restrict__ wqkvT,
    float* __restrict__ bqkv, unsigned short* __restrict__ woT) {
  __shared__ float ld[64][68];
  const int bid = blockIdx.x, tid = threadIdx.x;
  if (bid < 4096) {
    int i8 = (bid * 256 + tid) * 8;
    float4 a = *(const float4*)(src + i8);
    float4 b = *(const float4*)(src + i8 + 4);
    short8 o;
    o[0] = f2bf(a.x); o[1] = f2bf(a.y); o[2] = f2bf(a.z); o[3] = f2bf(a.w);
    o[4] = f2bf(b.x); o[5] = f2bf(b.y); o[6] = f2bf(b.z); o[7] = f2bf(b.w);
    *(short8*)(srcb + i8) = o;
  } else if (bid < 4864) {
    int idx = bid - 4096;
    int d0 = (idx & 15) * 64, h = (idx >> 4) & 15, z = idx >> 8;
    const float* W = (z == 0 ? Wq : z == 1 ? Wk : Wv) + (size_t)h * DD * DK;
    {
      int r = tid >> 2, c16 = (tid & 3) * 16;
#pragma unroll
      for (int i = 0; i < 4; ++i)
        *(float4*)(&ld[r][c16 + i * 4]) =
            *(const float4*)(W + (size_t)(d0 + r) * DK + c16 + i * 4);
    }
    __syncthreads();
    int dv = tid >> 2, d16 = (tid & 3) * 16;
    short8 o0, o1;
#pragma unroll
    for (int i = 0; i < 8; ++i) {
      o0[i] = f2bf(ld[d16 + i][dv]);
      o1[i] = f2bf(ld[d16 + 8 + i][dv]);
    }
    unsigned short* dst = wqkvT + (size_t)(z * 1024 + h * 64 + dv) * DD + d0 + d16;
    *(short8*)(dst) = o0;
    *(short8*)(dst + 8) = o1;
  } else if (bid < 4876) {
    int n = (bid - 4864) * 256 + tid;
    int z = n >> 10;
    const float* s = (z == 0 ? bq : z == 1 ? bk : bv);
    bqkv[n] = s[n & 1023];
  } else {
    int idx = bid - 4876;
    tr64(Wo, woT, 1024, 1024, (idx & 15) * 64, (idx >> 4) * 64, ld, tid);
  }
}

// ---------------------------------------------------------------------------
// prep2 (R10-proven): mask/w1T/w2T only (their write regions alias srcb/wqkvT,
// so this launches AFTER the QKV gemm consumes those).
//  [0,512)       maskb = bf16(mask * -1e9 * log2e)
//  [512,1536)    w1T [4096,1024]
//  [1536,2560)   w2T [1024,4096]
// ---------------------------------------------------------------------------
__global__ __launch_bounds__(256) void prep2(
    const float* __restrict__ mask,
    const float* __restrict__ W1, const float* __restrict__ W2,
    unsigned short* __restrict__ maskb, unsigned short* __restrict__ w1T,
    unsigned short* __restrict__ w2T) {
  __shared__ float ldf[64][68];
  const int bid = blockIdx.x, tid = threadIdx.x;
  if (bid < 512) {
    const float MS = -1.442695041e9f;
    int i8 = (bid * 256 + tid) * 8;
    float4 a = *(const float4*)(mask + i8);
    float4 b = *(const float4*)(mask + i8 + 4);
    short8 o;
    o[0] = f2bf(a.x * MS); o[1] = f2bf(a.y * MS);
    o[2] = f2bf(a.z * MS); o[3] = f2bf(a.w * MS);
    o[4] = f2bf(b.x * MS); o[5] = f2bf(b.y * MS);
    o[6] = f2bf(b.z * MS); o[7] = f2bf(b.w * MS);
    *(short8*)(maskb + i8) = o;
  } else if (bid < 1536) {
    int i = bid - 512;
    tr64(W1, w1T, 1024, 4096, (i & 15) * 64, (i >> 4) * 64, ldf, tid);
  } else {
    int i = bid - 1536;
    tr64(W2, w2T, 4096, 1024, (i & 63) * 64, (i >> 6) * 64, ldf, tid);
  }
}

// ---------------------------------------------------------------------------
// Shared schedule pieces (8-phase, counted vmcnt, raw s_barrier)
// ---------------------------------------------------------------------------
#define BARE __builtin_amdgcn_s_barrier()
#define VM6  asm volatile("s_waitcnt vmcnt(6)" ::: "memory")
#define VM4  asm volatile("s_waitcnt vmcnt(4)" ::: "memory")
#define VM0  asm volatile("s_waitcnt vmcnt(0)" ::: "memory")
#define PH_HINT asm volatile("s_waitcnt lgkmcnt(8)" ::: "memory")
#define PH_SYNC { \
  __builtin_amdgcn_s_barrier(); \
  asm volatile("s_waitcnt lgkmcnt(0)" ::: "memory"); \
  __builtin_amdgcn_sched_barrier(0); }

// ---------------------------------------------------------------------------
// gemm256: 256x256x(BK=64), 8 waves (2M x 4N), 512 threads, 128 KiB LDS.
// ---------------------------------------------------------------------------
#define LOAD_A(lA_, mh_) { \
  _Pragma("unroll") for (int m_ = 0; m_ < 4; ++m_) { \
    const int row_ = wr * 128 + (mh_) * 64 + m_ * 16 + lm; \
    _Pragma("unroll") for (int ks_ = 0; ks_ < 2; ++ks_) \
      a[m_][ks_] = *(const short8*)((lA_) + (size_t)row_ * 64 + \
                     (size_t)(((ks_ * 4 + quad) ^ (lm & 7)) * 8)); \
  } }

#define LOAD_B(lB_, nh_) { \
  _Pragma("unroll") for (int n_ = 0; n_ < 2; ++n_) { \
    const int row_ = wc * 64 + (nh_) * 32 + n_ * 16 + lm; \
    _Pragma("unroll") for (int ks_ = 0; ks_ < 2; ++ks_) \
      bfr[nh_][n_][ks_] = *(const short8*)((lB_) + 16384 + (size_t)row_ * 64 + \
                     (size_t)(((ks_ * 4 + quad) ^ (lm & 7)) * 8)); \
  } }

#define STAGE_A(kt_, mh_, lb_) { \
  _Pragma("unroll") for (int c_ = 0; c_ < 2; ++c_) { \
    const int row_ = c_ * 128 + (mh_) * 64; \
    gload_lds16(gA + (size_t)(kt_) * 64 + (size_t)row_ * K, \
                (lb_) + (size_t)(row_ + wave * 8) * 64); \
  } }

#define STAGE_B(kt_, nh_, lb_) { \
  _Pragma("unroll") for (int c_ = 0; c_ < 2; ++c_) { \
    const int row_ = c_ * 128 + hi128 + (nh_) * 32; \
    gload_lds16(gB + (size_t)(kt_) * 64 + (size_t)row_ * K, \
                (lb_) + 16384 + (size_t)(row_ + (wave & 3) * 8) * 64); \
  } }

#define MFMA_PH(mh_, nh_) { \
  __builtin_amdgcn_s_setprio(1); \
  _Pragma("unroll") for (int m_ = 0; m_ < 4; ++m_) \
    _Pragma("unroll") for (int n_ = 0; n_ < 2; ++n_) { \
      acc[(mh_) * 4 + m_][(nh_) * 2 + n_] = __builtin_amdgcn_mfma_f32_16x16x32_bf16( \
          bfr[nh_][n_][0], a[m_][0], acc[(mh_) * 4 + m_][(nh_) * 2 + n_], 0, 0, 0); \
      acc[(mh_) * 4 + m_][(nh_) * 2 + n_] = __builtin_amdgcn_mfma_f32_16x16x32_bf16( \
          bfr[nh_][n_][1], a[m_][1], acc[(mh_) * 4 + m_][(nh_) * 2 + n_], 0, 0, 0); \
    } \
  __builtin_amdgcn_s_setprio(0); }

// ST_ = 1: steady iteration (stages tiles e+2, e+3); ST_ = 0: peeled tail.
#define KITER(e_, ST_) { \
  LOAD_A(buf0, 0); LOAD_B(buf0, 0); \
  STAGE_B((e_) + 1, 1, buf1); \
  PH_HINT; PH_SYNC; MFMA_PH(0, 0); BARE; \
  LOAD_B(buf0, 1); \
  if (ST_) STAGE_A((e_) + 2, 0, buf0); \
  PH_SYNC; MFMA_PH(0, 1); BARE; \
  LOAD_A(buf0, 1); \
  if (ST_) STAGE_B((e_) + 2, 0, buf0); \
  PH_SYNC; MFMA_PH(1, 0); BARE; \
  if (ST_) STAGE_A((e_) + 2, 1, buf0); \
  PH_SYNC; MFMA_PH(1, 1); \
  if (ST_) { VM6; } else { VM0; } \
  BARE; \
  LOAD_A(buf1, 0); LOAD_B(buf1, 0); \
  if (ST_) STAGE_B((e_) + 2, 1, buf0); \
  PH_HINT; PH_SYNC; MFMA_PH(0, 0); BARE; \
  LOAD_B(buf1, 1); \
  if (ST_) STAGE_A((e_) + 3, 0, buf1); \
  PH_SYNC; MFMA_PH(0, 1); BARE; \
  LOAD_A(buf1, 1); \
  if (ST_) STAGE_B((e_) + 3, 0, buf1); \
  PH_SYNC; MFMA_PH(1, 0); BARE; \
  if (ST_) { \
    STAGE_A((e_) + 3, 1, buf1); \
    PH_SYNC; MFMA_PH(1, 1); VM6; BARE; \
  } else { \
    PH_SYNC; MFMA_PH(1, 1); \
  } }

template <int RELU>
__global__ __launch_bounds__(512, 2) void gemm256(
    const unsigned short* __restrict__ A, const unsigned short* __restrict__ Bt,
    const float* __restrict__ bias, unsigned short* __restrict__ C,
    int M, int N, int K) {
  extern __shared__ unsigned short lds[];  // [buf0 | buf1], each A16384|B16384
  unsigned short* buf0 = lds;
  unsigned short* buf1 = lds + 32768;
  const int tid = threadIdx.x;
  const int wave = tid >> 6, lane = tid & 63;
  const int lm = lane & 15, quad = lane >> 4;
  const int wr = wave >> 2, wc = wave & 3;

  // XCD-aware bijective swizzle (all grids here are multiples of 8)
  const int nwg = gridDim.x;
  const int cpx = nwg >> 3;
  const int id = (blockIdx.x & 7) * cpx + (blockIdx.x >> 3);
  const int nbx = N >> 8;
  const int bx = id % nbx, by = id / nbx;
  const int n0 = bx << 8, m0 = by << 8;

  const int NT = K >> 6;   // 64-wide K-tiles

  const int srow = tid >> 3;                    // 0..63
  const int chs = (tid & 7) ^ (srow & 7);
  const int hi128 = (tid >= 256) ? 64 : 0;
  const int r32 = (tid >> 3) & 31;
  const unsigned short* gA = A + (size_t)(m0 + srow) * K + chs * 8;
  const unsigned short* gB = Bt + (size_t)(n0 + r32) * K + chs * 8;

  floatx4 acc[8][4] = {};
  short8 a[4][2], bfr[2][2][2];

  // prologue: tile0 full (8 loads) + tile1 {A.h0, B.h0, A.h1} (6 loads)
  STAGE_A(0, 0, buf0); STAGE_B(0, 0, buf0);
  STAGE_A(0, 1, buf0); STAGE_B(0, 1, buf0);
  STAGE_A(1, 0, buf1); STAGE_B(1, 0, buf1);
  STAGE_A(1, 1, buf1);
  VM6;   // retire tile0's 8, leave tile1's 6 in flight
  BARE;

  const int TT = NT >> 1;
  for (int i = 0; i < TT - 1; ++i) {
    KITER(2 * i, 1);
  }
  KITER(NT - 2, 0);

  // epilogue: bias (+ReLU) + bf16 store, per-lane 8B stores
#pragma unroll
  for (int mi = 0; mi < 8; ++mi) {
    const int row = m0 + wr * 128 + mi * 16 + lm;
#pragma unroll
    for (int nj = 0; nj < 4; ++nj) {
      const int col = n0 + wc * 64 + nj * 16 + (quad << 2);
      const float4 bv = *(const float4*)(bias + col);
      float vv[4] = {acc[mi][nj][0] + bv.x, acc[mi][nj][1] + bv.y,
                     acc[mi][nj][2] + bv.z, acc[mi][nj][3] + bv.w};
      short4v o;
#pragma unroll
      for (int r = 0; r < 4; ++r) {
        float v = vv[r];
        if (RELU) v = fmaxf(v, 0.f);
        o[r] = f2bf(v);
      }
      *(short4v*)(C + (size_t)row * N + col) = o;
    }
  }
}

// ---------------------------------------------------------------------------
// gemm128: 128x256x(BK=64) variant of the SAME 8-phase schedule.
// kdst/vdst (optional): blocks whose n0 lies in [1024,2048) / [2048,3072)
// write output directly in kbb [bh][t][dk] / vtb [bh][dv][t] layouts.
// ---------------------------------------------------------------------------
#define LOAD_A1(lb_, mh_) { \
  _Pragma("unroll") for (int m_ = 0; m_ < 2; ++m_) { \
    const int row_ = wr * 64 + (mh_) * 32 + m_ * 16 + lm; \
    _Pragma("unroll") for (int ks_ = 0; ks_ < 2; ++ks_) \
      a[m_][ks_] = *(const short8*)((lb_) + (size_t)row_ * 64 + \
                     (size_t)(((ks_ * 4 + quad) ^ (lm & 7)) * 8)); \
  } }

#define LOAD_B1(lb_, nh_) { \
  _Pragma("unroll") for (int n_ = 0; n_ < 2; ++n_) { \
    const int row_ = wc * 64 + (nh_) * 32 + n_ * 16 + lm; \
    _Pragma("unroll") for (int ks_ = 0; ks_ < 2; ++ks_) \
      bfr[nh_][n_][ks_] = *(const short8*)((lb_) + 8192 + (size_t)row_ * 64 + \
                     (size_t)(((ks_ * 4 + quad) ^ (lm & 7)) * 8)); \
  } }

#define STAGE_A1(kt_, mh_, lb_) { \
  gload_lds16(gA + (size_t)(kt_) * 64 + (size_t)((mh_) * 32) * K, \
              (lb_) + (size_t)((mh_) * 32 + hi128 + (wave & 3) * 8) * 64); }

#define STAGE_B1(kt_, nh_, lb_) { \
  _Pragma("unroll") for (int c_ = 0; c_ < 2; ++c_) { \
    const int row_ = c_ * 128 + hi128 + (nh_) * 32; \
    gload_lds16(gB + (size_t)(kt_) * 64 + (size_t)row_ * K, \
                (lb_) + 8192 + (size_t)(row_ + (wave & 3) * 8) * 64); \
  } }

#define MFMA_PH1(mh_, nh_) { \
  __builtin_amdgcn_s_setprio(1); \
  _Pragma("unroll") for (int m_ = 0; m_ < 2; ++m_) \
    _Pragma("unroll") for (int n_ = 0; n_ < 2; ++n_) { \
      acc[(mh_) * 2 + m_][(nh_) * 2 + n_] = __builtin_amdgcn_mfma_f32_16x16x32_bf16( \
          bfr[nh_][n_][0], a[m_][0], acc[(mh_) * 2 + m_][(nh_) * 2 + n_], 0, 0, 0); \
      acc[(mh_) * 2 + m_][(nh_) * 2 + n_] = __builtin_amdgcn_mfma_f32_16x16x32_bf16( \
          bfr[nh_][n_][1], a[m_][1], acc[(mh_) * 2 + m_][(nh_) * 2 + n_], 0, 0, 0); \
    } \
  __builtin_amdgcn_s_setprio(0); }

#define KITER1(e_, ST_) { \
  LOAD_A1(buf0, 0); LOAD_B1(buf0, 0); \
  STAGE_B1((e_) + 1, 1, buf1); \
  PH_SYNC; MFMA_PH1(0, 0); BARE; \
  LOAD_B1(buf0, 1); \
  if (ST_) STAGE_A1((e_) + 2, 0, buf0); \
  PH_SYNC; MFMA_PH1(0, 1); BARE; \
  LOAD_A1(buf0, 1); \
  if (ST_) STAGE_B1((e_) + 2, 0, buf0); \
  PH_SYNC; MFMA_PH1(1, 0); BARE; \
  if (ST_) STAGE_A1((e_) + 2, 1, buf0); \
  PH_SYNC; MFMA_PH1(1, 1); \
  if (ST_) { VM4; } else { VM0; } \
  BARE; \
  LOAD_A1(buf1, 0); LOAD_B1(buf1, 0); \
  if (ST_) STAGE_B1((e_) + 2, 1, buf0); \
  PH_SYNC; MFMA_PH1(0, 0); BARE; \
  LOAD_B1(buf1, 1); \
  if (ST_) STAGE_A1((e_) + 3, 0, buf1); \
  PH_SYNC; MFMA_PH1(0, 1); BARE; \
  LOAD_A1(buf1, 1); \
  if (ST_) STAGE_B1((e_) + 3, 0, buf1); \
  PH_SYNC; MFMA_PH1(1, 0); BARE; \
  if (ST_) { \
    STAGE_A1((e_) + 3, 1, buf1); \
    PH_SYNC; MFMA_PH1(1, 1); VM4; BARE; \
  } else { \
    PH_SYNC; MFMA_PH1(1, 1); \
  } }

__global__ __launch_bounds__(512, 2) void gemm128(
    const unsigned short* __restrict__ A, const unsigned short* __restrict__ Bt,
    const float* __restrict__ bias, unsigned short* __restrict__ C,
    unsigned short* __restrict__ kdst, unsigned short* __restrict__ vdst,
    int M, int N, int K) {
  extern __shared__ unsigned short lds[];  // 2 bufs x (A 8192 | B 16384) elems
  unsigned short* buf0 = lds;
  unsigned short* buf1 = lds + 24576;
  const int tid = threadIdx.x;
  const int wave = tid >> 6, lane = tid & 63;
  const int lm = lane & 15, quad = lane >> 4;
  const int wr = wave >> 2, wc = wave & 3;

  const int nwg = gridDim.x;
  const int cpx = nwg >> 3;
  const int id = (blockIdx.x & 7) * cpx + (blockIdx.x >> 3);
  const int nbx = N >> 8;
  const int bx = id % nbx, by = id / nbx;
  const int n0 = bx << 8, m0 = by << 7;   // BM = 128

  const int NT = K >> 6;

  const int srow = tid >> 3;
  const int chs = (tid & 7) ^ (srow & 7);
  const int hi128 = (tid >= 256) ? 64 : 0;
  const int r32 = (tid >> 3) & 31;
  // A global row = m0 + hi128 + mh*32 + r32  (matches LDS row mh*32+hi128+r32)
  const unsigned short* gA = A + (size_t)(m0 + hi128 + r32) * K + chs * 8;
  const unsigned short* gB = Bt + (size_t)(n0 + r32) * K + chs * 8;

  floatx4 acc[4][4] = {};
  short8 a[2][2], bfr[2][2][2];

  // prologue: tile0 full (6 loads) + tile1 {A.H0, B.h0, A.H1} (4 loads)
  STAGE_A1(0, 0, buf0); STAGE_B1(0, 0, buf0);
  STAGE_A1(0, 1, buf0); STAGE_B1(0, 1, buf0);
  STAGE_A1(1, 0, buf1); STAGE_B1(1, 0, buf1);
  STAGE_A1(1, 1, buf1);
  VM4;   // retire tile0's 6, leave tile1's 4 in flight
  BARE;

  const int TT = NT >> 1;
  for (int i = 0; i < TT - 1; ++i) {
    KITER1(2 * i, 1);
  }
  KITER1(NT - 2, 0);

  const bool kdirect = (kdst != nullptr) && (n0 >= 1024) && (n0 < 2048);
  const bool vdirect = (vdst != nullptr) && (n0 >= 2048) && (n0 < 3072);
#pragma unroll
  for (int mi = 0; mi < 4; ++mi) {
    const int row = m0 + wr * 64 + mi * 16 + lm;
#pragma unroll
    for (int nj = 0; nj < 4; ++nj) {
      const int col = n0 + wc * 64 + nj * 16 + (quad << 2);
      const float4 bv = *(const float4*)(bias + col);
      short4v o;
      o[0] = f2bf(acc[mi][nj][0] + bv.x);
      o[1] = f2bf(acc[mi][nj][1] + bv.y);
      o[2] = f2bf(acc[mi][nj][2] + bv.z);
      o[3] = f2bf(acc[mi][nj][3] + bv.w);
      if (kdirect) {
        // kbb[(b*16+h)][t][dk]: b=row>>10, t=row&1023, h=(col-1024)>>6, dk=col&63
        const int b_ = row >> 10, t_ = row & 1023;
        const int rel = col - 1024;
        const int h_ = rel >> 6, dk = rel & 63;
        *(short4v*)(kdst + ((size_t)(b_ * 16 + h_) * 1024 + t_) * 64 + dk) = o;
      } else if (vdirect) {
        // vtb[(b*16+h)][dv][t]: dv = col&63 (4 consecutive dv per lane)
        const int b_ = row >> 10, t_ = row & 1023;
        const int rel = col - 2048;
        const int h_ = rel >> 6, dv = rel & 63;
        unsigned short* vp = vdst + ((size_t)(b_ * 16 + h_) * 64 + dv) * 1024 + t_;
        vp[0]    = (unsigned short)o[0];
        vp[1024] = (unsigned short)o[1];
        vp[2048] = (unsigned short)o[2];
        vp[3072] = (unsigned short)o[3];
      } else {
        *(short4v*)(C + (size_t)row * N + col) = o;
      }
    }
  }
}

// ---------------------------------------------------------------------------
// Flash attention. LDS cut 50KB -> 32KB (4 blocks/CU = 32 waves -> the full
// 1024-block grid resident in ONE round; was 3/CU + straggler round).
// Ps buffer eliminated: P is wave-private and each wave reads ONLY its own
// 16 Ms rows (mask consumed into registers, data-dep, before P-stores), so
// P aliases the wave's own Ms rows [wave*16,+16). Per-row 8B-granule XOR
// (g ^ lm) on store AND read (bijective; t-contiguous un-swizzled layout
// identical to the proven Ps layout). PV completes before the top-of-loop
// __syncthreads that guards next-tile Ms restaging.
// ---------------------------------------------------------------------------
__global__ __launch_bounds__(512) void attention_flash(
    const unsigned short* __restrict__ qkv, const unsigned short* __restrict__ kb,
    const unsigned short* __restrict__ vt, const unsigned short* __restrict__ maskb,
    unsigned short* __restrict__ ctx) {
  const int flat = blockIdx.x;
  const int bh = (flat & 7) + 8 * (flat >> 6);       // all q-tiles of a bh on one XCD
  const int qt = (flat >> 3) & 7;
  const int b = bh >> 4, h = bh & 15;
  const int s0 = qt * 128;
  const int tid = threadIdx.x;
  const int wave = tid >> 6, lane = tid & 63;
  const int lm = lane & 15, quad = lane >> 4;

  __shared__ __align__(16) unsigned short Ks[64 * 64];     //  8 KB swizzled [t][dk]
  __shared__ __align__(16) unsigned short Vs[64 * 64];     //  8 KB swizzled [dv][t]
  __shared__ __align__(16) unsigned short Ms[128 * 64];    // 16 KB swizzled [q][t]; P aliases per-wave rows

  // Q fragments (once): q-row = s0 + wave*16 + lm
  const unsigned short* qp = qkv + (size_t)(b * SS + s0 + wave * 16 + lm) * 3072 + h * 64;
  const short8 qa0 = *(const short8*)(qp + quad * 8);
  const short8 qa1 = *(const short8*)(qp + quad * 8 + 32);

  const unsigned short* kbase = kb + (size_t)bh * SS * DK;   // [t][dk]
  const unsigned short* vbase = vt + (size_t)bh * DK * SS;   // [dv][t]
  const unsigned short* mbase = maskb + (size_t)s0 * SS;     // [q][t]

  const int sr = lane >> 3, sj = lane & 7;   // staging row-in-8 / chunk
  const int srr = wave * 8 + sr;
  const unsigned short* ksrc = kbase + (size_t)srr * 64 + (size_t)(sj ^ (srr & 7)) * 8;
  const int qr = wave * 16 + lm;
  unsigned short* pr = &Ms[(unsigned)qr * 64];   // wave-private P rows (alias)
  float m_run = -3e38f, l_run = 0.f;
  floatx4 O[4] = {};

  for (int it = 0; it < 16; ++it) {
    const int t0 = it * 64;
    __syncthreads();   // previous compute done before tiles overwritten
    {
      // K: slots [wave*64, +64): r = srr, chunk = sj^(r&7)
      gload_lds16(ksrc + (size_t)t0 * 64, (char*)Ks + wave * 1024);
      // V^T: r = dv
      gload_lds16(vbase + (size_t)srr * SS + t0 + (size_t)(sj ^ (srr & 7)) * 8,
                  (char*)Vs + wave * 1024);
      // mask: 2 slots per thread
      int q1 = wave * 8 + sr;
      gload_lds16(mbase + (size_t)q1 * SS + t0 + (size_t)(sj ^ (q1 & 7)) * 8,
                  (char*)Ms + wave * 1024);
      int q2 = 64 + wave * 8 + sr;
      gload_lds16(mbase + (size_t)q2 * SS + t0 + (size_t)(sj ^ (q2 & 7)) * 8,
                  (char*)Ms + 8192 + wave * 1024);
    }
    __syncthreads();

    // ---- S = K-tile x Q (D[t][q]); lane collects 16 t-values for q=lm ----
    float p[16];
#pragma unroll
    for (int ts = 0; ts < 4; ++ts) {
      int r = ts * 16 + lm;
      short8 kf0 = *(const short8*)&Ks[(r * 8 + (quad ^ (r & 7))) * 8];
      short8 kf1 = *(const short8*)&Ks[(r * 8 + ((quad + 4) ^ (r & 7))) * 8];
      floatx4 c = {0.f, 0.f, 0.f, 0.f};
      c = __builtin_amdgcn_mfma_f32_16x16x32_bf16(kf0, qa0, c, 0, 0, 0);
      c = __builtin_amdgcn_mfma_f32_16x16x32_bf16(kf1, qa1, c, 0, 0, 0);
      int mj = (ts * 2 + (quad >> 1)) ^ (qr & 7);
      short4v mv = *(const short4v*)&Ms[(qr * 8 + mj) * 8 + (quad & 1) * 4];
#pragma unroll
      for (int r2 = 0; r2 < 4; ++r2) {
        // exp2-domain score: qk * 0.125 * log2e + (mask * -1e9 * log2e)
        p[ts * 4 + r2] = c[r2] * 0.18033688011112042f + bf2f((unsigned short)mv[r2]);
      }
    }
    // max tree (clang fuses to v_max3_f32)
    float m0a = fmaxf(fmaxf(p[0], p[1]), p[2]);
    float m0b = fmaxf(fmaxf(p[3], p[4]), p[5]);
    float m0c = fmaxf(fmaxf(p[6], p[7]), p[8]);
    float m0d = fmaxf(fmaxf(p[9], p[10]), p[11]);
    float m0e = fmaxf(fmaxf(p[12], p[13]), p[14]);
    float mt = fmaxf(fmaxf(fmaxf(m0a, m0b), m0c), fmaxf(fmaxf(m0d, m0e), p[15]));
    mt = fmaxf(mt, __shfl_xor(mt, 16));
    mt = fmaxf(mt, __shfl_xor(mt, 32));
    // T13 defer-max (log2 domain): THR = 8*log2e -> P bounded by e^8.
    if (!__all(mt - m_run <= 11.541560327f)) {
      float mnew = fmaxf(m_run, mt);
      float alpha = __builtin_amdgcn_exp2f(m_run - mnew);
#pragma unroll
      for (int d = 0; d < 4; ++d)
#pragma unroll
        for (int r2 = 0; r2 < 4; ++r2) O[d][r2] *= alpha;
      l_run *= alpha;
      m_run = mnew;
    }
    float psum = 0.f;
#pragma unroll
    for (int i = 0; i < 16; ++i) {
      p[i] = __builtin_amdgcn_exp2f(p[i] - m_run);
      psum += p[i];
    }
    psum += __shfl_xor(psum, 16);
    psum += __shfl_xor(psum, 32);
    l_run += psum;

    // ---- P -> wave's own Ms rows (alias; mask already consumed above).
    // Granule g = (ts*4+quad)^lm holds t-values [ts*16+quad*4,+4) (bijective,
    // t-contiguous un-swizzled — same logical layout as the proven Ps). ----
#pragma unroll
    for (int ts = 0; ts < 4; ++ts) {
      unsigned plo, phi;
      asm("v_cvt_pk_bf16_f32 %0, %1, %2" : "=v"(plo) : "v"(p[ts * 4 + 0]), "v"(p[ts * 4 + 1]));
      asm("v_cvt_pk_bf16_f32 %0, %1, %2" : "=v"(phi) : "v"(p[ts * 4 + 2]), "v"(p[ts * 4 + 3]));
      uint2 pu; pu.x = plo; pu.y = phi;
      *(uint2*)(pr + (((ts * 4 + quad) ^ lm) << 2)) = pu;
    }

    // ---- PV: O^T[dv][q] += V^T-tile x P^T ----
#pragma unroll
    for (int ks = 0; ks < 2; ++ks) {
      union { unsigned u[4]; short8 s; } pf;
      {
        const int gb = ks * 8 + quad * 2;
        uint2 lo = *(const uint2*)(pr + (((gb) ^ lm) << 2));
        uint2 hi = *(const uint2*)(pr + (((gb + 1) ^ lm) << 2));
        pf.u[0] = lo.x; pf.u[1] = lo.y; pf.u[2] = hi.x; pf.u[3] = hi.y;
      }
#pragma unroll
      for (int d = 0; d < 4; ++d) {
        int dv = d * 16 + lm;
        short8 vf = *(const short8*)&Vs[(dv * 8 + ((ks * 4 + quad) ^ (dv & 7))) * 8];
        O[d] = __builtin_amdgcn_mfma_f32_16x16x32_bf16(vf, pf.s, O[d], 0, 0, 0);
      }
    }
  }

  // ---- epilogue: normalize, store ctx[b, s0+qr, h*64+dv] ----
  const float inv = 1.f / l_run;
  unsigned short* cp = ctx + (size_t)(b * SS + s0 + wave * 16 + lm) * DD + h * 64;
#pragma unroll
  for (int d = 0; d < 4; ++d) {
    short4v o;
#pragma unroll
    for (int r2 = 0; r2 < 4; ++r2) o[r2] = f2bf(O[d][r2] * inv);
    *(short4v*)(cp + d * 16 + quad * 4) = o;
  }
}

// ---------------------------------------------------------------------------
// Residual + LayerNorm: out = LN(a + r) * w + b. One block per row (D=1024).
// ---------------------------------------------------------------------------
template <int A_BF16, int OUT_BF16>
__global__ __launch_bounds__(256) void residual_ln(
    const void* __restrict__ a_, const unsigned short* __restrict__ rr,
    const float* __restrict__ w, const float* __restrict__ bias,
    void* __restrict__ out_) {
  const int row = blockIdx.x;
  const int t = threadIdx.x;
  float x[4];
  if (A_BF16) {
    short4v va = *(const short4v*)((const unsigned short*)a_ + (size_t)row * DD + t * 4);
#pragma unroll
    for (int i = 0; i < 4; ++i) x[i] = bf2f((unsigned short)va[i]);
  } else {
    float4 va = *(const float4*)((const float*)a_ + (size_t)row * DD + t * 4);
    x[0] = va.x; x[1] = va.y; x[2] = va.z; x[3] = va.w;
  }
  {
    short4v vr = *(const short4v*)(rr + (size_t)row * DD + t * 4);
#pragma unroll
    for (int i = 0; i < 4; ++i) x[i] += bf2f((unsigned short)vr[i]);
  }
  float s = 0.f, ss = 0.f;
#pragma unroll
  for (int i = 0; i < 4; ++i) { s += x[i]; ss += x[i] * x[i]; }
#pragma unroll
  for (int o = 32; o > 0; o >>= 1) {
    s  += __shfl_down(s, o);
    ss += __shfl_down(ss, o);
  }
  __shared__ float2 sred[4];
  int wid = t >> 6;
  if ((t & 63) == 0) sred[wid] = make_float2(s, ss);
  __syncthreads();
  float st = 0.f, sst = 0.f;
#pragma unroll
  for (int i = 0; i < 4; ++i) { st += sred[i].x; sst += sred[i].y; }
  float mu  = st * (1.f / 1024.f);
  float var = sst * (1.f / 1024.f) - mu * mu;
  float rsq = rsqrtf(var + 1e-5f);
  float4 vw = *(const float4*)(w + t * 4);
  float4 vb = *(const float4*)(bias + t * 4);
  float o[4];
  o[0] = (x[0] - mu) * rsq * vw.x + vb.x;
  o[1] = (x[1] - mu) * rsq * vw.y + vb.y;
  o[2] = (x[2] - mu) * rsq * vw.z + vb.z;
  o[3] = (x[3] - mu) * rsq * vw.w + vb.w;
  if (OUT_BF16) {
    short4v ov;
#pragma unroll
    for (int i = 0; i < 4; ++i) ov[i] = f2bf(o[i]);
    *(short4v*)((unsigned short*)out_ + (size_t)row * DD + t * 4) = ov;
  } else {
    float4 ov = {o[0], o[1], o[2], o[3]};
    *(float4*)((float*)out_ + (size_t)row * DD + t * 4) = ov;
  }
}

// ---------------------------------------------------------------------------
extern "C" void kernel_launch(void* const* d_in, const int* in_sizes, int n_in,
                              void* d_out, int out_size, void* d_ws, size_t ws_size,
                              hipStream_t stream) {
  const float* src  = (const float*)d_in[0];
  const float* mask = (const float*)d_in[1];
  const float* Wq = (const float*)d_in[2];  const float* bq = (const float*)d_in[3];
  const float* Wk = (const float*)d_in[4];  const float* bk = (const float*)d_in[5];
  const float* Wv = (const float*)d_in[6];  const float* bv = (const float*)d_in[7];
  const float* Wo = (const float*)d_in[8];  const float* bo = (const float*)d_in[9];
  const float* ln1w = (const float*)d_in[10]; const float* ln1b = (const float*)d_in[11];
  const float* W1 = (const float*)d_in[12]; const float* b1 = (const float*)d_in[13];
  const float* W2 = (const float*)d_in[14]; const float* b2 = (const float*)d_in[15];
  const float* ln2w = (const float*)d_in[16]; const float* ln2b = (const float*)d_in[17];
  float* out = (float*)d_out;

  // Workspace (total 125,841,408 B, same as proven):
  const size_t NEED = 125841408;
  if (ws_size < NEED) return;

  char* ws = (char*)d_ws;
  unsigned short* qkv   = (unsigned short*)(ws);
  unsigned short* vtb   = (unsigned short*)(ws + 50331648);
  unsigned short* kbb   = (unsigned short*)(ws + 67108864);
  unsigned short* ctxb  = (unsigned short*)(ws + 83886080);
  unsigned short* srcb  = (unsigned short*)(ws + 100663296);
  unsigned short* w1T   = (unsigned short*)(ws + 100663296);  // [4096,1024] (after QKV)
  unsigned short* w2T   = (unsigned short*)(ws + 109051904);  // [1024,4096]
  unsigned short* wqkvT = (unsigned short*)(ws + 117440512);  // [3072,1024]
  unsigned short* maskb = (unsigned short*)(ws + 117440512);  // [S,S] bf16 (after QKV)
  unsigned short* woT   = (unsigned short*)(ws + 123731968);  // [1024,1024]
  float*          bqkv  = (float*)(ws + 125829120);           // [3072]
  unsigned short* h1       = qkv;                             // [M,4096] = [0,64M)
  unsigned short* attn_out = kbb;
  unsigned short* xb       = ctxb;
  unsigned short* ffn      = kbb;

  static bool lds_init = false;
  if (!lds_init) {
    auto* k1 = gemm256<1>;
    hipFuncSetAttribute((const void*)k1, hipFuncAttributeMaxDynamicSharedMemorySize, 131072);
    hipFuncSetAttribute((const void*)gemm128, hipFuncAttributeMaxDynamicSharedMemorySize, 98304);
    lds_init = true;
  }

  prep_all<<<5132, 256, 0, stream>>>(src, Wq, Wk, Wv, bq, bk, bv, Wo,
                                     srcb, wqkvT, bqkv, woT);
  // QKV: [8192,3072]; K-slice -> kbb layout, V-slice -> vtb layout (direct)
  gemm128<<<(3072 / 256) * (MM / 128), 512, 98304, stream>>>(srcb, wqkvT, bqkv, qkv, kbb, vtb, MM, 3072, DD);
  // mask/w1T/w2T (write regions alias srcb/wqkvT -> must follow QKV gemm)
  prep2<<<2560, 256, 0, stream>>>(mask, W1, W2, maskb, w1T, w2T);
  attention_flash<<<1024, 512, 0, stream>>>(qkv, kbb, vtb, maskb, ctxb);
  // Wo: [8192,1024] (BM=128 -> 256 blocks, full machine)
  gemm128<<<(DD / 256) * (MM / 128), 512, 98304, stream>>>(ctxb, woT, bo, attn_out, nullptr, nullptr, MM, DD, DD);
  residual_ln<0, 1><<<MM, 256, 0, stream>>>(src, attn_out, ln1w, ln1b, xb);
  // FFN1: [8192,4096] (256^2 -> 512 blocks)
  gemm256<1><<<(FF / 256) * (MM / 256), 512, 131072, stream>>>(xb, w1T, b1, h1, MM, FF, DD);
  // FFN2: [8192,1024], K=4096 (BM=128 -> 256 blocks, full machine)
  gemm128<<<(DD / 256) * (MM / 128), 512, 98304, stream>>>(h1, w2T, b2, ffn, nullptr, nullptr, MM, DD, FF);
  residual_ln<1, 0><<<MM, 256, 0, stream>>>(xb, ffn, ln2w, ln2b, out);
}